// Round 1
// baseline (21630.202 us; speedup 1.0000x reference)
//
#include <hip/hip_runtime.h>

#define B_ 32
#define T_ 2048
#define D_ 512
#define H_ 512
#define G4 2048
#define NWG 8      // recurrence workgroups (8 waves each); WG owns 64 hidden units
#define WVW 8      // waves per WG

typedef short short8 __attribute__((ext_vector_type(8)));
typedef float floatv16 __attribute__((ext_vector_type(16)));
typedef float floatv4 __attribute__((ext_vector_type(4)));

static __device__ __forceinline__ unsigned short f2bf(float f) {
  union { float f; unsigned u; } v; v.f = f;
  unsigned u = v.u;
  u += 0x7fffu + ((u >> 16) & 1u);
  return (unsigned short)(u >> 16);
}
static __device__ __forceinline__ float bf2f(unsigned short h) {
  union { unsigned u; float f; } v; v.u = ((unsigned)h) << 16;
  return v.f;
}
static __device__ __forceinline__ float sigm(float x) { return 1.0f / (1.0f + __expf(-x)); }
static __device__ __forceinline__ float tanh_(float x) {
  float e = __expf(-2.0f * fabsf(x));
  float t = (1.0f - e) / (1.0f + e);
  return copysignf(t, x);
}

#define MFMA32(A, Bv, C) __builtin_amdgcn_mfma_f32_32x32x16_bf16((A), (Bv), (C), 0, 0, 0)

// ---------------- convert / prep kernel ----------------
__global__ __launch_bounds__(256) void cvt_kernel(
    const float* __restrict__ Wih, const float* __restrict__ Whh,
    const float* __restrict__ bih, const float* __restrict__ bhh,
    const float* __restrict__ h0, const float* __restrict__ c0,
    short* __restrict__ wih_hi, short* __restrict__ wih_lo, short* __restrict__ whh_hi,
    float* __restrict__ bias, short* __restrict__ hbuf0, float* __restrict__ cws) {
  int i = blockIdx.x * 256 + threadIdx.x;
  if (i < G4 * D_) {
    float w = Wih[i];
    unsigned short hi = f2bf(w);
    wih_hi[i] = (short)hi;
    wih_lo[i] = (short)f2bf(w - bf2f(hi));
    whh_hi[i] = (short)f2bf(Whh[i]);
  }
  if (i < G4) bias[i] = bih[i] + bhh[i];
  if (i < B_ * H_) { hbuf0[i] = (short)f2bf(h0[i]); cws[i] = c0[i]; }
}

// ---------------- phase A: x_proj GEMM (split-bf16, 3 MFMA) ----------------
// xp[t][n][b] = sum_d input[b][t][d] * W_ih[n][d] + (b_ih[n] + b_hh[n])
__global__ __launch_bounds__(256, 1) void xproj_kernel(
    const float* __restrict__ input,
    const short* __restrict__ wih_hi, const short* __restrict__ wih_lo,
    const float* __restrict__ bias, float* __restrict__ xp, int t0, int TC) {
  __shared__ short xlo_lds[4 * 8192];
  const int tid = threadIdx.x;
  const int wv = tid >> 6, l = tid & 63;
  const int wid = blockIdx.x * 4 + wv;
  const int lt = wid >> 3, nb = wid & 7;
  const int t = t0 + lt;
  const int lb = l & 31, hb = l >> 5;
  const float* xrow = input + ((size_t)lb * T_ + t) * D_ + hb * 8;
  short* slo = xlo_lds + wv * 8192;
  short8 xhi[32];
#pragma unroll
  for (int kb = 0; kb < 32; ++kb) {
    floatv4 x0 = *(const floatv4*)(xrow + kb * 16);
    floatv4 x1 = *(const floatv4*)(xrow + kb * 16 + 4);
    float xs[8] = {x0[0], x0[1], x0[2], x0[3], x1[0], x1[1], x1[2], x1[3]};
    short8 hi, lo;
#pragma unroll
    for (int j = 0; j < 8; ++j) {
      unsigned short h = f2bf(xs[j]);
      hi[j] = (short)h;
      lo[j] = (short)f2bf(xs[j] - bf2f(h));
    }
    xhi[kb] = hi;
    *(short8*)(slo + (kb * 64 + l) * 8) = lo;
  }
  for (int nt = 0; nt < 8; ++nt) {
    const int n0 = nb * 256 + nt * 32;
    const short* whbase = wih_hi + (size_t)(n0 + lb) * D_ + hb * 8;
    const short* wlbase = wih_lo + (size_t)(n0 + lb) * D_ + hb * 8;
    floatv16 a0, a1;
#pragma unroll
    for (int i = 0; i < 16; ++i) { a0[i] = 0.0f; a1[i] = 0.0f; }
#pragma unroll
    for (int kb = 0; kb < 32; ++kb) {
      short8 whi = *(const short8*)(whbase + kb * 16);
      short8 wlo = *(const short8*)(wlbase + kb * 16);
      short8 xl = *(const short8*)(slo + (kb * 64 + l) * 8);
      a0 = MFMA32(whi, xhi[kb], a0);      // hi * hi
      a1 = MFMA32(whi, xl, a1);           // Whi * xlo
      a1 = MFMA32(wlo, xhi[kb], a1);      // Wlo * xhi
    }
#pragma unroll
    for (int r = 0; r < 16; ++r) {
      int row = (r & 3) + 8 * (r >> 2) + 4 * hb;
      int n = n0 + row;
      xp[((size_t)lt * G4 + n) * B_ + lb] = a0[r] + a1[r] + bias[n];
    }
  }
}

// ---------------- recurrence kernel ----------------
// 8 WGs x 512 threads (8 waves). Global wave gw in [0,64) owns hidden units
// [gw*8, gw*8+8) -> 32 W_hh rows persistent in 128 VGPRs (unchanged layout).
// Sync consolidated per-WG: one flag per WG (8 flags), published after
// __syncthreads() drains all 8 waves' h stores. Consumers poll 8 cachelines
// (coalesced) with RELAXED agent loads + a single acquire fence on detect.
__global__ __launch_bounds__(512, 2) void lstm_rec(
    const float* __restrict__ xp, const short* __restrict__ whh,
    short* __restrict__ hbuf, float* __restrict__ cws, int* __restrict__ flags,
    float* __restrict__ out, int t0, int TC, int writeOut) {
  const int wv = threadIdx.x >> 6;
  const int l = threadIdx.x & 63;
  const int gw = blockIdx.x * WVW + wv;               // 0..63
  const int lb = l & 31, hb = l >> 5;
  const int nl = lb;                                  // A row = n_local
  const int ngl = (nl >> 3) * H_ + gw * 8 + (nl & 7); // row in W_hh [2048 x 512]
  short8 Wf[32];
#pragma unroll
  for (int kb = 0; kb < 32; ++kb)
    Wf[kb] = *(const short8*)(whh + (size_t)ngl * H_ + kb * 16 + hb * 8);
  float c4[4], h4[4];
#pragma unroll
  for (int q = 0; q < 4; ++q) c4[q] = cws[lb * H_ + gw * 8 + 4 * hb + q];

  for (int t = t0; t < t0 + TC; ++t) {
    // prefetch x_proj for this step (independent of h, hide under the wait)
    const float* xpt = xp + (size_t)(t - t0) * G4 * B_;
    float xpv[16];
#pragma unroll
    for (int g = 0; g < 4; ++g)
#pragma unroll
      for (int q = 0; q < 4; ++q)
        xpv[g * 4 + q] = xpt[(size_t)(g * H_ + gw * 8 + 4 * hb + q) * B_ + lb];

    if (t > 0) {  // wait for all 8 producer WGs to have published h_t
      int v;
      do {
        v = __hip_atomic_load(flags + (l & 7) * 16, __ATOMIC_RELAXED, __HIP_MEMORY_SCOPE_AGENT);
      } while (!__all(v >= t));
      __builtin_amdgcn_fence(__ATOMIC_ACQUIRE, "agent");
    }

    const short* hsrc = hbuf + (t & 1) * (B_ * H_) + lb * H_ + hb * 8;
    floatv16 D0, D1;
#pragma unroll
    for (int i = 0; i < 16; ++i) { D0[i] = 0.0f; D1[i] = 0.0f; }
#pragma unroll
    for (int kb = 0; kb < 32; kb += 2) {  // 2 independent MFMA chains
      short8 hf0 = *(const short8*)(hsrc + kb * 16);
      short8 hf1 = *(const short8*)(hsrc + kb * 16 + 16);
      D0 = MFMA32(Wf[kb], hf0, D0);
      D1 = MFMA32(Wf[kb + 1], hf1, D1);
    }

    union { unsigned short s[4]; unsigned long long u; } pk;
#pragma unroll
    for (int q = 0; q < 4; ++q) {
      float gi = D0[q] + D1[q] + xpv[q];
      float gf = D0[4 + q] + D1[4 + q] + xpv[4 + q];
      float gg = D0[8 + q] + D1[8 + q] + xpv[8 + q];
      float go = D0[12 + q] + D1[12 + q] + xpv[12 + q];
      float iv = sigm(gi), fv = sigm(gf), gv = tanh_(gg), ov = sigm(go);
      c4[q] = fv * c4[q] + iv * gv;
      h4[q] = ov * tanh_(c4[q]);
      pk.s[q] = f2bf(h4[q]);
    }
    unsigned long long* hdst = (unsigned long long*)(hbuf + ((t + 1) & 1) * (B_ * H_) +
                                                     lb * H_ + gw * 8 + 4 * hb);
    __hip_atomic_store(hdst, pk.u, __ATOMIC_RELAXED, __HIP_MEMORY_SCOPE_AGENT);
    // all 8 waves' h stores drained (vmcnt(0)) at the barrier, then one
    // release-store publishes the whole WG's slice.
    __syncthreads();
    if (threadIdx.x == 0)
      __hip_atomic_store(flags + blockIdx.x * 16, t + 1, __ATOMIC_RELEASE, __HIP_MEMORY_SCOPE_AGENT);
  }

#pragma unroll
  for (int q = 0; q < 4; ++q) cws[lb * H_ + gw * 8 + 4 * hb + q] = c4[q];
  if (writeOut) {
#pragma unroll
    for (int q = 0; q < 4; ++q) {
      out[lb * H_ + gw * 8 + 4 * hb + q] = h4[q];                 // final h
      out[B_ * H_ + lb * H_ + gw * 8 + 4 * hb + q] = c4[q];       // final c
    }
  }
}

extern "C" void kernel_launch(void* const* d_in, const int* in_sizes, int n_in,
                              void* d_out, int out_size, void* d_ws, size_t ws_size,
                              hipStream_t stream) {
  (void)in_sizes; (void)n_in; (void)out_size;
  const float* input = (const float*)d_in[0];
  const float* h0 = (const float*)d_in[1];
  const float* c0 = (const float*)d_in[2];
  const float* Wih = (const float*)d_in[3];
  const float* Whh = (const float*)d_in[4];
  const float* bih = (const float*)d_in[5];
  const float* bhh = (const float*)d_in[6];

  char* ws = (char*)d_ws;
  short* wih_hi = (short*)(ws);
  short* wih_lo = (short*)(ws + (2ull << 20));
  short* whh_hi = (short*)(ws + (4ull << 20));
  float* bias = (float*)(ws + (6ull << 20));
  short* hbuf = (short*)(ws + (6ull << 20) + 65536);
  float* cws = (float*)(ws + (6ull << 20) + 131072);
  int* flags = (int*)(ws + (6ull << 20) + 196608);
  float* xp = (float*)(ws + (8ull << 20));

  // chunk size adapted to workspace: xp needs TC*2048*32*4 bytes after 8MB reserve
  int TC = 32;
  while (TC < 2048 && (8ull << 20) + (size_t)(TC * 2) * (G4 * B_ * 4) <= ws_size) TC <<= 1;

  hipMemsetAsync(flags, 0, 4096, stream);
  cvt_kernel<<<dim3((G4 * D_ + 255) / 256), dim3(256), 0, stream>>>(
      Wih, Whh, bih, bhh, h0, c0, wih_hi, wih_lo, whh_hi, bias, hbuf, cws);
  for (int t0 = 0; t0 < T_; t0 += TC) {
    int tc = (t0 + TC <= T_) ? TC : (T_ - t0);
    xproj_kernel<<<dim3(tc * 2), dim3(256), 0, stream>>>(input, wih_hi, wih_lo, bias, xp, t0, tc);
    lstm_rec<<<dim3(NWG), dim3(512), 0, stream>>>(xp, whh_hi, hbuf, cws, flags,
                                                  (float*)d_out, t0, tc,
                                                  (t0 + tc) == T_ ? 1 : 0);
  }
}

// Round 2
// 15450.819 us; speedup vs baseline: 1.3999x; 1.3999x over previous
//
#include <hip/hip_runtime.h>

#define B_ 32
#define T_ 2048
#define D_ 512
#define H_ 512
#define G4 2048
#define NWG 64   // recurrence workgroups (1 wave each), each owns 8 hidden units

typedef short short8 __attribute__((ext_vector_type(8)));
typedef float floatv16 __attribute__((ext_vector_type(16)));
typedef float floatv4 __attribute__((ext_vector_type(4)));

static __device__ __forceinline__ unsigned short f2bf(float f) {
  union { float f; unsigned u; } v; v.f = f;
  unsigned u = v.u;
  u += 0x7fffu + ((u >> 16) & 1u);
  return (unsigned short)(u >> 16);
}
static __device__ __forceinline__ float bf2f(unsigned short h) {
  union { unsigned u; float f; } v; v.u = ((unsigned)h) << 16;
  return v.f;
}
static __device__ __forceinline__ float sigm(float x) { return 1.0f / (1.0f + __expf(-x)); }
static __device__ __forceinline__ float tanh_(float x) {
  float e = __expf(-2.0f * fabsf(x));
  float t = (1.0f - e) / (1.0f + e);
  return copysignf(t, x);
}

#define MFMA32(A, Bv, C) __builtin_amdgcn_mfma_f32_32x32x16_bf16((A), (Bv), (C), 0, 0, 0)

// ---------------- convert / prep kernel ----------------
__global__ __launch_bounds__(256) void cvt_kernel(
    const float* __restrict__ Wih, const float* __restrict__ Whh,
    const float* __restrict__ bih, const float* __restrict__ bhh,
    const float* __restrict__ h0, const float* __restrict__ c0,
    short* __restrict__ wih_hi, short* __restrict__ wih_lo, short* __restrict__ whh_hi,
    float* __restrict__ bias, short* __restrict__ hbuf0, float* __restrict__ cws) {
  int i = blockIdx.x * 256 + threadIdx.x;
  if (i < G4 * D_) {
    float w = Wih[i];
    unsigned short hi = f2bf(w);
    wih_hi[i] = (short)hi;
    wih_lo[i] = (short)f2bf(w - bf2f(hi));
    whh_hi[i] = (short)f2bf(Whh[i]);
  }
  if (i < G4) bias[i] = bih[i] + bhh[i];
  if (i < B_ * H_) { hbuf0[i] = (short)f2bf(h0[i]); cws[i] = c0[i]; }
}

// ---------------- phase A: x_proj GEMM (split-bf16, 3 MFMA) ----------------
// xp[t][n][b] = sum_d input[b][t][d] * W_ih[n][d] + (b_ih[n] + b_hh[n])
__global__ __launch_bounds__(256, 1) void xproj_kernel(
    const float* __restrict__ input,
    const short* __restrict__ wih_hi, const short* __restrict__ wih_lo,
    const float* __restrict__ bias, float* __restrict__ xp, int t0, int TC) {
  __shared__ short xlo_lds[4 * 8192];
  const int tid = threadIdx.x;
  const int wv = tid >> 6, l = tid & 63;
  const int wid = blockIdx.x * 4 + wv;
  const int lt = wid >> 3, nb = wid & 7;
  const int t = t0 + lt;
  const int lb = l & 31, hb = l >> 5;
  const float* xrow = input + ((size_t)lb * T_ + t) * D_ + hb * 8;
  short* slo = xlo_lds + wv * 8192;
  short8 xhi[32];
#pragma unroll
  for (int kb = 0; kb < 32; ++kb) {
    floatv4 x0 = *(const floatv4*)(xrow + kb * 16);
    floatv4 x1 = *(const floatv4*)(xrow + kb * 16 + 4);
    float xs[8] = {x0[0], x0[1], x0[2], x0[3], x1[0], x1[1], x1[2], x1[3]};
    short8 hi, lo;
#pragma unroll
    for (int j = 0; j < 8; ++j) {
      unsigned short h = f2bf(xs[j]);
      hi[j] = (short)h;
      lo[j] = (short)f2bf(xs[j] - bf2f(h));
    }
    xhi[kb] = hi;
    *(short8*)(slo + (kb * 64 + l) * 8) = lo;
  }
  for (int nt = 0; nt < 8; ++nt) {
    const int n0 = nb * 256 + nt * 32;
    const short* whbase = wih_hi + (size_t)(n0 + lb) * D_ + hb * 8;
    const short* wlbase = wih_lo + (size_t)(n0 + lb) * D_ + hb * 8;
    floatv16 a0, a1;
#pragma unroll
    for (int i = 0; i < 16; ++i) { a0[i] = 0.0f; a1[i] = 0.0f; }
#pragma unroll
    for (int kb = 0; kb < 32; ++kb) {
      short8 whi = *(const short8*)(whbase + kb * 16);
      short8 wlo = *(const short8*)(wlbase + kb * 16);
      short8 xl = *(const short8*)(slo + (kb * 64 + l) * 8);
      a0 = MFMA32(whi, xhi[kb], a0);      // hi * hi
      a1 = MFMA32(whi, xl, a1);           // Whi * xlo
      a1 = MFMA32(wlo, xhi[kb], a1);      // Wlo * xhi
    }
#pragma unroll
    for (int r = 0; r < 16; ++r) {
      int row = (r & 3) + 8 * (r >> 2) + 4 * hb;
      int n = n0 + row;
      xp[((size_t)lt * G4 + n) * B_ + lb] = a0[r] + a1[r] + bias[n];
    }
  }
}

// ---------------- recurrence kernel ----------------
// 64 WGs x 64 threads (1 wave) — proven structure. WG w owns hidden units
// [w*8, w*8+8). Sync topology changed only:
//  - publish: one fetch_add(RELEASE) per wave on group counter (w>>3): 8 lines,
//    8 adders each. Monotone counters, no reset races across chunk dispatches.
//  - poll: lanes read 8 group lines (l&7) RELAXED; wait grp >= 8*t; one
//    acquire fence on detect (instead of a cache-inv per poll iteration).
__global__ __launch_bounds__(64, 1) void lstm_rec(
    const float* __restrict__ xp, const short* __restrict__ whh,
    short* __restrict__ hbuf, float* __restrict__ cws, int* __restrict__ flags,
    float* __restrict__ out, int t0, int TC, int writeOut) {
  const int w = blockIdx.x;
  const int l = threadIdx.x;
  const int lb = l & 31, hb = l >> 5;
  const int nl = lb;                                  // A row = n_local
  const int ngl = (nl >> 3) * H_ + w * 8 + (nl & 7);  // row in W_hh [2048 x 512]
  short8 Wf[32];
#pragma unroll
  for (int kb = 0; kb < 32; ++kb)
    Wf[kb] = *(const short8*)(whh + (size_t)ngl * H_ + kb * 16 + hb * 8);
  float c4[4], h4[4];
#pragma unroll
  for (int q = 0; q < 4; ++q) c4[q] = cws[lb * H_ + w * 8 + 4 * hb + q];

  for (int t = t0; t < t0 + TC; ++t) {
    // prefetch x_proj for this step (independent of h, hide under the wait)
    const float* xpt = xp + (size_t)(t - t0) * G4 * B_;
    float xpv[16];
#pragma unroll
    for (int g = 0; g < 4; ++g)
#pragma unroll
      for (int q = 0; q < 4; ++q)
        xpv[g * 4 + q] = xpt[(size_t)(g * H_ + w * 8 + 4 * hb + q) * B_ + lb];

    if (t > 0) {  // wait for all 8 producer groups (8 waves each) at step t
      const int want = 8 * t;
      int v;
      do {
        v = __hip_atomic_load(flags + (l & 7) * 16, __ATOMIC_RELAXED, __HIP_MEMORY_SCOPE_AGENT);
      } while (!__all(v >= want));
      __builtin_amdgcn_fence(__ATOMIC_ACQUIRE, "agent");
    }

    const short* hsrc = hbuf + (t & 1) * (B_ * H_) + lb * H_ + hb * 8;
    floatv16 D0, D1;
#pragma unroll
    for (int i = 0; i < 16; ++i) { D0[i] = 0.0f; D1[i] = 0.0f; }
#pragma unroll
    for (int kb = 0; kb < 32; kb += 2) {  // 2 independent MFMA chains
      short8 hf0 = *(const short8*)(hsrc + kb * 16);
      short8 hf1 = *(const short8*)(hsrc + kb * 16 + 16);
      D0 = MFMA32(Wf[kb], hf0, D0);
      D1 = MFMA32(Wf[kb + 1], hf1, D1);
    }

    union { unsigned short s[4]; unsigned long long u; } pk;
#pragma unroll
    for (int q = 0; q < 4; ++q) {
      float gi = D0[q] + D1[q] + xpv[q];
      float gf = D0[4 + q] + D1[4 + q] + xpv[4 + q];
      float gg = D0[8 + q] + D1[8 + q] + xpv[8 + q];
      float go = D0[12 + q] + D1[12 + q] + xpv[12 + q];
      float iv = sigm(gi), fv = sigm(gf), gv = tanh_(gg), ov = sigm(go);
      c4[q] = fv * c4[q] + iv * gv;
      h4[q] = ov * tanh_(c4[q]);
      pk.s[q] = f2bf(h4[q]);
    }
    unsigned long long* hdst = (unsigned long long*)(hbuf + ((t + 1) & 1) * (B_ * H_) +
                                                     lb * H_ + w * 8 + 4 * hb);
    __hip_atomic_store(hdst, pk.u, __ATOMIC_RELAXED, __HIP_MEMORY_SCOPE_AGENT);
    if (l == 0)  // RELEASE drains this wave's h stores (vmcnt(0)), then counts
      __hip_atomic_fetch_add(flags + (w >> 3) * 16, 1, __ATOMIC_RELEASE,
                             __HIP_MEMORY_SCOPE_AGENT);
  }

#pragma unroll
  for (int q = 0; q < 4; ++q) cws[lb * H_ + w * 8 + 4 * hb + q] = c4[q];
  if (writeOut) {
#pragma unroll
    for (int q = 0; q < 4; ++q) {
      out[lb * H_ + w * 8 + 4 * hb + q] = h4[q];                 // final h
      out[B_ * H_ + lb * H_ + w * 8 + 4 * hb + q] = c4[q];       // final c
    }
  }
}

extern "C" void kernel_launch(void* const* d_in, const int* in_sizes, int n_in,
                              void* d_out, int out_size, void* d_ws, size_t ws_size,
                              hipStream_t stream) {
  (void)in_sizes; (void)n_in; (void)out_size;
  const float* input = (const float*)d_in[0];
  const float* h0 = (const float*)d_in[1];
  const float* c0 = (const float*)d_in[2];
  const float* Wih = (const float*)d_in[3];
  const float* Whh = (const float*)d_in[4];
  const float* bih = (const float*)d_in[5];
  const float* bhh = (const float*)d_in[6];

  char* ws = (char*)d_ws;
  short* wih_hi = (short*)(ws);
  short* wih_lo = (short*)(ws + (2ull << 20));
  short* whh_hi = (short*)(ws + (4ull << 20));
  float* bias = (float*)(ws + (6ull << 20));
  short* hbuf = (short*)(ws + (6ull << 20) + 65536);
  float* cws = (float*)(ws + (6ull << 20) + 131072);
  int* flags = (int*)(ws + (6ull << 20) + 196608);
  float* xp = (float*)(ws + (8ull << 20));

  // chunk size adapted to workspace: xp needs TC*2048*32*4 bytes after 8MB reserve
  int TC = 32;
  while (TC < 256 && (8ull << 20) + (size_t)(TC * 2) * (G4 * B_ * 4) <= ws_size) TC <<= 1;

  hipMemsetAsync(flags, 0, 4096, stream);
  cvt_kernel<<<dim3((G4 * D_ + 255) / 256), dim3(256), 0, stream>>>(
      Wih, Whh, bih, bhh, h0, c0, wih_hi, wih_lo, whh_hi, bias, hbuf, cws);
  for (int t0 = 0; t0 < T_; t0 += TC) {
    xproj_kernel<<<dim3(TC * 2), dim3(256), 0, stream>>>(input, wih_hi, wih_lo, bias, xp, t0, TC);
    lstm_rec<<<dim3(NWG), dim3(64), 0, stream>>>(xp, whh_hi, hbuf, cws, flags,
                                                 (float*)d_out, t0, TC,
                                                 (t0 + TC) == T_ ? 1 : 0);
  }
}

// Round 3
// 14444.858 us; speedup vs baseline: 1.4974x; 1.0696x over previous
//
#include <hip/hip_runtime.h>

#define B_ 32
#define T_ 2048
#define D_ 512
#define H_ 512
#define G4 2048
#define NWG 64   // recurrence workgroups (1 wave each), each owns 8 hidden units

typedef short short8 __attribute__((ext_vector_type(8)));
typedef float floatv16 __attribute__((ext_vector_type(16)));
typedef float floatv4 __attribute__((ext_vector_type(4)));

static __device__ __forceinline__ unsigned short f2bf(float f) {
  union { float f; unsigned u; } v; v.f = f;
  unsigned u = v.u;
  u += 0x7fffu + ((u >> 16) & 1u);
  return (unsigned short)(u >> 16);
}
static __device__ __forceinline__ float bf2f(unsigned short h) {
  union { unsigned u; float f; } v; v.u = ((unsigned)h) << 16;
  return v.f;
}
static __device__ __forceinline__ float sigm(float x) { return 1.0f / (1.0f + __expf(-x)); }
static __device__ __forceinline__ float tanh_(float x) {
  float e = __expf(-2.0f * fabsf(x));
  float t = (1.0f - e) / (1.0f + e);
  return copysignf(t, x);
}

#define MFMA32(A, Bv, C) __builtin_amdgcn_mfma_f32_32x32x16_bf16((A), (Bv), (C), 0, 0, 0)

// ---------------- convert / prep kernel ----------------
// hbuf layout is wave-major: [wave w][batch b][8 units], 16B per (w,b).
// Producer wave w's whole payload is one contiguous 512B burst; consumer's
// per-kb MFMA fragment read is 1KB contiguous.
__global__ __launch_bounds__(256) void cvt_kernel(
    const float* __restrict__ Wih, const float* __restrict__ Whh,
    const float* __restrict__ bih, const float* __restrict__ bhh,
    const float* __restrict__ h0, const float* __restrict__ c0,
    short* __restrict__ wih_hi, short* __restrict__ wih_lo, short* __restrict__ whh_hi,
    float* __restrict__ bias, short* __restrict__ hbuf0, float* __restrict__ cws) {
  int i = blockIdx.x * 256 + threadIdx.x;
  if (i < G4 * D_) {
    float w = Wih[i];
    unsigned short hi = f2bf(w);
    wih_hi[i] = (short)hi;
    wih_lo[i] = (short)f2bf(w - bf2f(hi));
    whh_hi[i] = (short)f2bf(Whh[i]);
  }
  if (i < G4) bias[i] = bih[i] + bhh[i];
  if (i < B_ * H_) {
    int b = i / H_, h = i % H_;
    hbuf0[((h >> 3) * B_ + b) * 8 + (h & 7)] = (short)f2bf(h0[i]);
    cws[i] = c0[i];
  }
}

// ---------------- phase A: x_proj GEMM (split-bf16, 3 MFMA) ----------------
// xp[t][n][b] = sum_d input[b][t][d] * W_ih[n][d] + (b_ih[n] + b_hh[n])
__global__ __launch_bounds__(256, 1) void xproj_kernel(
    const float* __restrict__ input,
    const short* __restrict__ wih_hi, const short* __restrict__ wih_lo,
    const float* __restrict__ bias, float* __restrict__ xp, int t0, int TC) {
  __shared__ short xlo_lds[4 * 8192];
  const int tid = threadIdx.x;
  const int wv = tid >> 6, l = tid & 63;
  const int wid = blockIdx.x * 4 + wv;
  const int lt = wid >> 3, nb = wid & 7;
  const int t = t0 + lt;
  const int lb = l & 31, hb = l >> 5;
  const float* xrow = input + ((size_t)lb * T_ + t) * D_ + hb * 8;
  short* slo = xlo_lds + wv * 8192;
  short8 xhi[32];
#pragma unroll
  for (int kb = 0; kb < 32; ++kb) {
    floatv4 x0 = *(const floatv4*)(xrow + kb * 16);
    floatv4 x1 = *(const floatv4*)(xrow + kb * 16 + 4);
    float xs[8] = {x0[0], x0[1], x0[2], x0[3], x1[0], x1[1], x1[2], x1[3]};
    short8 hi, lo;
#pragma unroll
    for (int j = 0; j < 8; ++j) {
      unsigned short h = f2bf(xs[j]);
      hi[j] = (short)h;
      lo[j] = (short)f2bf(xs[j] - bf2f(h));
    }
    xhi[kb] = hi;
    *(short8*)(slo + (kb * 64 + l) * 8) = lo;
  }
  for (int nt = 0; nt < 8; ++nt) {
    const int n0 = nb * 256 + nt * 32;
    const short* whbase = wih_hi + (size_t)(n0 + lb) * D_ + hb * 8;
    const short* wlbase = wih_lo + (size_t)(n0 + lb) * D_ + hb * 8;
    floatv16 a0, a1;
#pragma unroll
    for (int i = 0; i < 16; ++i) { a0[i] = 0.0f; a1[i] = 0.0f; }
#pragma unroll
    for (int kb = 0; kb < 32; ++kb) {
      short8 whi = *(const short8*)(whbase + kb * 16);
      short8 wlo = *(const short8*)(wlbase + kb * 16);
      short8 xl = *(const short8*)(slo + (kb * 64 + l) * 8);
      a0 = MFMA32(whi, xhi[kb], a0);      // hi * hi
      a1 = MFMA32(whi, xl, a1);           // Whi * xlo
      a1 = MFMA32(wlo, xhi[kb], a1);      // Wlo * xhi
    }
#pragma unroll
    for (int r = 0; r < 16; ++r) {
      int row = (r & 3) + 8 * (r >> 2) + 4 * hb;
      int n = n0 + row;
      xp[((size_t)lt * G4 + n) * B_ + lb] = a0[r] + a1[r] + bias[n];
    }
  }
}

// ---------------- recurrence kernel ----------------
// 64 WGs x 64 threads (1 wave). WG w owns hidden units [w*8, w*8+8).
// Round-0 sync (per-wave release-store flags) + wave-major hbuf layout:
//  - producer h store: ONE contiguous 512B burst (4 lines) -> fast vmcnt drain
//  - consumer fragment load: 1KB contiguous per kb (8 lines, 100% utilized)
//    vs old [b][h] layout's 32-line 12.5%-utilized gathers.
// Poll: RELAXED loads + single acquire fence on detect.
__global__ __launch_bounds__(64, 1) void lstm_rec(
    const float* __restrict__ xp, const short* __restrict__ whh,
    short* __restrict__ hbuf, float* __restrict__ cws, int* __restrict__ flags,
    float* __restrict__ out, int t0, int TC, int writeOut) {
  const int w = blockIdx.x;
  const int l = threadIdx.x;
  const int lb = l & 31, hb = l >> 5;
  const int nl = lb;                                  // A row = n_local
  const int ngl = (nl >> 3) * H_ + w * 8 + (nl & 7);  // row in W_hh [2048 x 512]
  short8 Wf[32];
#pragma unroll
  for (int kb = 0; kb < 32; ++kb)
    Wf[kb] = *(const short8*)(whh + (size_t)ngl * H_ + kb * 16 + hb * 8);
  float c4[4], h4[4];
#pragma unroll
  for (int q = 0; q < 4; ++q) c4[q] = cws[lb * H_ + w * 8 + 4 * hb + q];

  for (int t = t0; t < t0 + TC; ++t) {
    // prefetch x_proj for this step (independent of h, hide under the wait)
    const float* xpt = xp + (size_t)(t - t0) * G4 * B_;
    float xpv[16];
#pragma unroll
    for (int g = 0; g < 4; ++g)
#pragma unroll
      for (int q = 0; q < 4; ++q)
        xpv[g * 4 + q] = xpt[(size_t)(g * H_ + w * 8 + 4 * hb + q) * B_ + lb];

    if (t > 0) {  // wait for all 64 producers to have published h_t
      int v;
      do {
        v = __hip_atomic_load(flags + l * 16, __ATOMIC_RELAXED, __HIP_MEMORY_SCOPE_AGENT);
      } while (!__all(v >= t));
      __builtin_amdgcn_fence(__ATOMIC_ACQUIRE, "agent");
    }

    // wave-major h_t: fragment for kb lives at [(2kb+hb)*B_ + lb] * 8 shorts
    const short* hbase = hbuf + (t & 1) * (B_ * H_);
    floatv16 D0, D1;
#pragma unroll
    for (int i = 0; i < 16; ++i) { D0[i] = 0.0f; D1[i] = 0.0f; }
#pragma unroll
    for (int kb = 0; kb < 32; kb += 2) {  // 2 independent MFMA chains
      short8 hf0 = *(const short8*)(hbase + ((2 * kb + hb) * B_ + lb) * 8);
      short8 hf1 = *(const short8*)(hbase + ((2 * kb + 2 + hb) * B_ + lb) * 8);
      D0 = MFMA32(Wf[kb], hf0, D0);
      D1 = MFMA32(Wf[kb + 1], hf1, D1);
    }

    union { unsigned short s[4]; unsigned long long u; } pk;
#pragma unroll
    for (int q = 0; q < 4; ++q) {
      float gi = D0[q] + D1[q] + xpv[q];
      float gf = D0[4 + q] + D1[4 + q] + xpv[4 + q];
      float gg = D0[8 + q] + D1[8 + q] + xpv[8 + q];
      float go = D0[12 + q] + D1[12 + q] + xpv[12 + q];
      float iv = sigm(gi), fv = sigm(gf), gv = tanh_(gg), ov = sigm(go);
      c4[q] = fv * c4[q] + iv * gv;
      h4[q] = ov * tanh_(c4[q]);
      pk.s[q] = f2bf(h4[q]);
    }
    // wave-major store: lane writes 8B at [w*B_ + lb]*16 + hb*8 -> wave's 512B
    // payload is contiguous (4 lines), so the release drain is one burst.
    unsigned long long* hdst = (unsigned long long*)(hbuf + ((t + 1) & 1) * (B_ * H_) +
                                                     (w * B_ + lb) * 8 + 4 * hb);
    __hip_atomic_store(hdst, pk.u, __ATOMIC_RELAXED, __HIP_MEMORY_SCOPE_AGENT);
    if (l == 0)
      __hip_atomic_store(flags + w * 16, t + 1, __ATOMIC_RELEASE, __HIP_MEMORY_SCOPE_AGENT);
  }

#pragma unroll
  for (int q = 0; q < 4; ++q) cws[lb * H_ + w * 8 + 4 * hb + q] = c4[q];
  if (writeOut) {
#pragma unroll
    for (int q = 0; q < 4; ++q) {
      out[lb * H_ + w * 8 + 4 * hb + q] = h4[q];                 // final h
      out[B_ * H_ + lb * H_ + w * 8 + 4 * hb + q] = c4[q];       // final c
    }
  }
}

extern "C" void kernel_launch(void* const* d_in, const int* in_sizes, int n_in,
                              void* d_out, int out_size, void* d_ws, size_t ws_size,
                              hipStream_t stream) {
  (void)in_sizes; (void)n_in; (void)out_size;
  const float* input = (const float*)d_in[0];
  const float* h0 = (const float*)d_in[1];
  const float* c0 = (const float*)d_in[2];
  const float* Wih = (const float*)d_in[3];
  const float* Whh = (const float*)d_in[4];
  const float* bih = (const float*)d_in[5];
  const float* bhh = (const float*)d_in[6];

  char* ws = (char*)d_ws;
  short* wih_hi = (short*)(ws);
  short* wih_lo = (short*)(ws + (2ull << 20));
  short* whh_hi = (short*)(ws + (4ull << 20));
  float* bias = (float*)(ws + (6ull << 20));
  short* hbuf = (short*)(ws + (6ull << 20) + 65536);
  float* cws = (float*)(ws + (6ull << 20) + 131072);
  int* flags = (int*)(ws + (6ull << 20) + 196608);
  float* xp = (float*)(ws + (8ull << 20));

  // chunk size adapted to workspace: xp needs TC*2048*32*4 bytes after 8MB reserve
  int TC = 32;
  while (TC < 256 && (8ull << 20) + (size_t)(TC * 2) * (G4 * B_ * 4) <= ws_size) TC <<= 1;

  hipMemsetAsync(flags, 0, 4096, stream);
  cvt_kernel<<<dim3((G4 * D_ + 255) / 256), dim3(256), 0, stream>>>(
      Wih, Whh, bih, bhh, h0, c0, wih_hi, wih_lo, whh_hi, bias, hbuf, cws);
  for (int t0 = 0; t0 < T_; t0 += TC) {
    xproj_kernel<<<dim3(TC * 2), dim3(256), 0, stream>>>(input, wih_hi, wih_lo, bias, xp, t0, TC);
    lstm_rec<<<dim3(NWG), dim3(64), 0, stream>>>(xp, whh_hi, hbuf, cws, flags,
                                                 (float*)d_out, t0, TC,
                                                 (t0 + TC) == T_ ? 1 : 0);
  }
}

// Round 7
// 12691.601 us; speedup vs baseline: 1.7043x; 1.1381x over previous
//
#include <hip/hip_runtime.h>

#define B_ 32
#define T_ 2048
#define D_ 512
#define H_ 512
#define G4 2048
#define NREC 64    // recurrence blocks (1 wave each), each owns 8 hidden units
#define NWRK 192   // xproj worker blocks (1 wave each) in the fused dispatch

typedef short short8 __attribute__((ext_vector_type(8)));
typedef float floatv16 __attribute__((ext_vector_type(16)));
typedef float floatv4 __attribute__((ext_vector_type(4)));

static __device__ __forceinline__ unsigned short f2bf(float f) {
  union { float f; unsigned u; } v; v.f = f;
  unsigned u = v.u;
  u += 0x7fffu + ((u >> 16) & 1u);
  return (unsigned short)(u >> 16);
}
static __device__ __forceinline__ float bf2f(unsigned short h) {
  union { unsigned u; float f; } v; v.u = ((unsigned)h) << 16;
  return v.f;
}
static __device__ __forceinline__ float sigm(float x) { return 1.0f / (1.0f + __expf(-x)); }
static __device__ __forceinline__ float tanh_(float x) {
  float e = __expf(-2.0f * fabsf(x));
  float t = (1.0f - e) / (1.0f + e);
  return copysignf(t, x);
}

#define MFMA32(A, Bv, C) __builtin_amdgcn_mfma_f32_32x32x16_bf16((A), (Bv), (C), 0, 0, 0)

// ---------------- convert / prep kernel (round-0 verbatim) ----------------
__global__ __launch_bounds__(256) void cvt_kernel(
    const float* __restrict__ Wih, const float* __restrict__ Whh,
    const float* __restrict__ bih, const float* __restrict__ bhh,
    const float* __restrict__ h0, const float* __restrict__ c0,
    short* __restrict__ wih_hi, short* __restrict__ wih_lo, short* __restrict__ whh_hi,
    float* __restrict__ bias, short* __restrict__ hbuf0, float* __restrict__ cws) {
  int i = blockIdx.x * 256 + threadIdx.x;
  if (i < G4 * D_) {
    float w = Wih[i];
    unsigned short hi = f2bf(w);
    wih_hi[i] = (short)hi;
    wih_lo[i] = (short)f2bf(w - bf2f(hi));
    whh_hi[i] = (short)f2bf(Whh[i]);
  }
  if (i < G4) bias[i] = bih[i] + bhh[i];
  if (i < B_ * H_) { hbuf0[i] = (short)f2bf(h0[i]); cws[i] = c0[i]; }
}

// ---------------- phase A: x_proj GEMM for chunk 0 (round-0 verbatim) --------
__global__ __launch_bounds__(256, 1) void xproj_kernel(
    const float* __restrict__ input,
    const short* __restrict__ wih_hi, const short* __restrict__ wih_lo,
    const float* __restrict__ bias, float* __restrict__ xp, int t0, int TC) {
  __shared__ short xlo_lds[4 * 8192];
  const int tid = threadIdx.x;
  const int wv = tid >> 6, l = tid & 63;
  const int wid = blockIdx.x * 4 + wv;
  const int lt = wid >> 3, nb = wid & 7;
  const int t = t0 + lt;
  const int lb = l & 31, hb = l >> 5;
  const float* xrow = input + ((size_t)lb * T_ + t) * D_ + hb * 8;
  short* slo = xlo_lds + wv * 8192;
  short8 xhi[32];
#pragma unroll
  for (int kb = 0; kb < 32; ++kb) {
    floatv4 x0 = *(const floatv4*)(xrow + kb * 16);
    floatv4 x1 = *(const floatv4*)(xrow + kb * 16 + 4);
    float xs[8] = {x0[0], x0[1], x0[2], x0[3], x1[0], x1[1], x1[2], x1[3]};
    short8 hi, lo;
#pragma unroll
    for (int j = 0; j < 8; ++j) {
      unsigned short h = f2bf(xs[j]);
      hi[j] = (short)h;
      lo[j] = (short)f2bf(xs[j] - bf2f(h));
    }
    xhi[kb] = hi;
    *(short8*)(slo + (kb * 64 + l) * 8) = lo;
  }
  for (int nt = 0; nt < 8; ++nt) {
    const int n0 = nb * 256 + nt * 32;
    const short* whbase = wih_hi + (size_t)(n0 + lb) * D_ + hb * 8;
    const short* wlbase = wih_lo + (size_t)(n0 + lb) * D_ + hb * 8;
    floatv16 a0, a1;
#pragma unroll
    for (int i = 0; i < 16; ++i) { a0[i] = 0.0f; a1[i] = 0.0f; }
#pragma unroll
    for (int kb = 0; kb < 32; ++kb) {
      short8 whi = *(const short8*)(whbase + kb * 16);
      short8 wlo = *(const short8*)(wlbase + kb * 16);
      short8 xl = *(const short8*)(slo + (kb * 64 + l) * 8);
      a0 = MFMA32(whi, xhi[kb], a0);      // hi * hi
      a1 = MFMA32(whi, xl, a1);           // Whi * xlo
      a1 = MFMA32(wlo, xhi[kb], a1);      // Wlo * xhi
    }
#pragma unroll
    for (int r = 0; r < 16; ++r) {
      int row = (r & 3) + 8 * (r >> 2) + 4 * hb;
      int n = n0 + row;
      xp[((size_t)lt * G4 + n) * B_ + lb] = a0[r] + a1[r] + bias[n];
    }
  }
}

// ---------------- fused per-chunk kernel ----------------
// blocks 0..63   : ROUND-0 recurrence body, chunk [t0, t0+TC) reading xpc
//                  (fully written by the PREVIOUS dispatch — stream order).
// blocks 64..255 : xproj workers producing chunk t0+TC into xpn (if doNext).
// NO dependency from rec on same-dispatch workers -> deadlock-impossible.
__global__ __launch_bounds__(64, 1) void fused_step(
    const float* __restrict__ input,
    const short* __restrict__ wih_hi, const short* __restrict__ wih_lo,
    const float* __restrict__ bias, const short* __restrict__ whh,
    short* __restrict__ hbuf, float* __restrict__ cws, int* __restrict__ flags,
    const float* __restrict__ xpc, float* __restrict__ xpn,
    float* __restrict__ out, int t0, int TC, int writeOut, int doNext) {
  __shared__ short slo[16384];  // worker staging (32KB, exact 1-wave footprint)
  const int l = threadIdx.x;
  const int lb = l & 31, hb = l >> 5;

  if (blockIdx.x < NREC) {
    // ---------------- recurrence role (round-0 verbatim) ----------------
    const int w = blockIdx.x;
    const int ngl = (lb >> 3) * H_ + w * 8 + (lb & 7);  // row in W_hh [2048x512]
    short8 Wf[32];
#pragma unroll
    for (int kb = 0; kb < 32; ++kb)
      Wf[kb] = *(const short8*)(whh + (size_t)ngl * H_ + kb * 16 + hb * 8);
    float c4[4], h4[4];
#pragma unroll
    for (int q = 0; q < 4; ++q) c4[q] = cws[lb * H_ + w * 8 + 4 * hb + q];

    for (int t = t0; t < t0 + TC; ++t) {
      // prefetch x_proj for this step (independent of h, hide under the wait)
      const float* xpt = xpc + (size_t)(t - t0) * G4 * B_;
      float xpv[16];
#pragma unroll
      for (int g = 0; g < 4; ++g)
#pragma unroll
        for (int q = 0; q < 4; ++q)
          xpv[g * 4 + q] = xpt[(size_t)(g * H_ + w * 8 + 4 * hb + q) * B_ + lb];

      if (t > 0) {  // wait for all 64 producers to have published h_t
        int v;
        do {
          v = __hip_atomic_load(flags + l * 16, __ATOMIC_ACQUIRE, __HIP_MEMORY_SCOPE_AGENT);
        } while (!__all(v >= t));
      }

      const short* hsrc = hbuf + (t & 1) * (B_ * H_) + lb * H_ + hb * 8;
      floatv16 D0, D1;
#pragma unroll
      for (int i = 0; i < 16; ++i) { D0[i] = 0.0f; D1[i] = 0.0f; }
#pragma unroll
      for (int kb = 0; kb < 32; kb += 2) {  // 2 independent MFMA chains
        short8 hf0 = *(const short8*)(hsrc + kb * 16);
        short8 hf1 = *(const short8*)(hsrc + kb * 16 + 16);
        D0 = MFMA32(Wf[kb], hf0, D0);
        D1 = MFMA32(Wf[kb + 1], hf1, D1);
      }

      union { unsigned short s[4]; unsigned long long u; } pk;
#pragma unroll
      for (int q = 0; q < 4; ++q) {
        float gi = D0[q] + D1[q] + xpv[q];
        float gf = D0[4 + q] + D1[4 + q] + xpv[4 + q];
        float gg = D0[8 + q] + D1[8 + q] + xpv[8 + q];
        float go = D0[12 + q] + D1[12 + q] + xpv[12 + q];
        float iv = sigm(gi), fv = sigm(gf), gv = tanh_(gg), ov = sigm(go);
        c4[q] = fv * c4[q] + iv * gv;
        h4[q] = ov * tanh_(c4[q]);
        pk.s[q] = f2bf(h4[q]);
      }
      unsigned long long* hdst = (unsigned long long*)(hbuf + ((t + 1) & 1) * (B_ * H_) +
                                                       lb * H_ + w * 8 + 4 * hb);
      __hip_atomic_store(hdst, pk.u, __ATOMIC_RELAXED, __HIP_MEMORY_SCOPE_AGENT);
      if (l == 0)
        __hip_atomic_store(flags + w * 16, t + 1, __ATOMIC_RELEASE, __HIP_MEMORY_SCOPE_AGENT);
    }

#pragma unroll
    for (int q = 0; q < 4; ++q) cws[lb * H_ + w * 8 + 4 * hb + q] = c4[q];
    if (writeOut) {
#pragma unroll
      for (int q = 0; q < 4; ++q) {
        out[lb * H_ + w * 8 + 4 * hb + q] = h4[q];                 // final h
        out[B_ * H_ + lb * H_ + w * 8 + 4 * hb + q] = c4[q];       // final c
      }
    }
  } else if (doNext) {
    // ---------------- xproj worker role: produce chunk t0+TC into xpn -------
    const int wkr = blockIdx.x - NREC;
    const int t0n = t0 + TC;
    for (int j = wkr; j < TC * 8; j += NWRK) {
      const int lt = j >> 3, nb = j & 7;
      const int t = t0n + lt;
      const float* xrow = input + ((size_t)lb * T_ + t) * D_ + hb * 8;
      short8 xhi[32];
#pragma unroll
      for (int kb = 0; kb < 32; ++kb) {
        floatv4 x0 = *(const floatv4*)(xrow + kb * 16);
        floatv4 x1 = *(const floatv4*)(xrow + kb * 16 + 4);
        float xs[8] = {x0[0], x0[1], x0[2], x0[3], x1[0], x1[1], x1[2], x1[3]};
        short8 hi, lo;
#pragma unroll
        for (int jj = 0; jj < 8; ++jj) {
          unsigned short h = f2bf(xs[jj]);
          hi[jj] = (short)h;
          lo[jj] = (short)f2bf(xs[jj] - bf2f(h));
        }
        xhi[kb] = hi;
        *(short8*)(slo + (kb * 64 + l) * 8) = lo;
      }
      for (int nt = 0; nt < 8; ++nt) {
        const int n0 = nb * 256 + nt * 32;
        const short* whbase = wih_hi + (size_t)(n0 + lb) * D_ + hb * 8;
        const short* wlbase = wih_lo + (size_t)(n0 + lb) * D_ + hb * 8;
        floatv16 a0, a1;
#pragma unroll
        for (int i = 0; i < 16; ++i) { a0[i] = 0.0f; a1[i] = 0.0f; }
#pragma unroll
        for (int kb = 0; kb < 32; ++kb) {
          short8 whi = *(const short8*)(whbase + kb * 16);
          short8 wlo = *(const short8*)(wlbase + kb * 16);
          short8 xl = *(const short8*)(slo + (kb * 64 + l) * 8);
          a0 = MFMA32(whi, xhi[kb], a0);      // hi * hi
          a1 = MFMA32(whi, xl, a1);           // Whi * xlo
          a1 = MFMA32(wlo, xhi[kb], a1);      // Wlo * xhi
        }
#pragma unroll
        for (int r = 0; r < 16; ++r) {
          int row = (r & 3) + 8 * (r >> 2) + 4 * hb;
          int n = n0 + row;
          xpn[((size_t)lt * G4 + n) * B_ + lb] = a0[r] + a1[r] + bias[n];
        }
      }
    }
  }
}

extern "C" void kernel_launch(void* const* d_in, const int* in_sizes, int n_in,
                              void* d_out, int out_size, void* d_ws, size_t ws_size,
                              hipStream_t stream) {
  (void)in_sizes; (void)n_in; (void)out_size;
  const float* input = (const float*)d_in[0];
  const float* h0 = (const float*)d_in[1];
  const float* c0 = (const float*)d_in[2];
  const float* Wih = (const float*)d_in[3];
  const float* Whh = (const float*)d_in[4];
  const float* bih = (const float*)d_in[5];
  const float* bhh = (const float*)d_in[6];

  char* ws = (char*)d_ws;
  short* wih_hi = (short*)(ws);
  short* wih_lo = (short*)(ws + (2ull << 20));
  short* whh_hi = (short*)(ws + (4ull << 20));
  float* bias = (float*)(ws + (6ull << 20));
  short* hbuf = (short*)(ws + (6ull << 20) + 65536);
  float* cws = (float*)(ws + (6ull << 20) + 131072);
  int* flags = (int*)(ws + (6ull << 20) + 196608);

  // chunk size: double-buffered xp needs 8MB + 2*TC*256KB <= ws_size
  // (identical arithmetic to the proven round-0 allocation; TC reaches 256)
  int TC = 32;
  while (TC < 256 && (8ull << 20) + (size_t)(TC * 2) * (G4 * B_ * 4) <= ws_size) TC <<= 1;
  const int nch = T_ / TC;
  float* xpA = (float*)(ws + (8ull << 20));
  float* xpB = xpA + (size_t)TC * G4 * B_;

  hipMemsetAsync(flags, 0, 4096, stream);
  cvt_kernel<<<dim3((G4 * D_ + 255) / 256), dim3(256), 0, stream>>>(
      Wih, Whh, bih, bhh, h0, c0, wih_hi, wih_lo, whh_hi, bias, hbuf, cws);
  // chunk 0's xp via the standalone (full-width) xproj
  xproj_kernel<<<dim3(TC * 2), dim3(256), 0, stream>>>(input, wih_hi, wih_lo, bias,
                                                       xpA, 0, TC);
  for (int k = 0; k < nch; ++k) {
    float* cur = (k & 1) ? xpB : xpA;
    float* nxt = (k & 1) ? xpA : xpB;
    fused_step<<<dim3(NREC + NWRK), dim3(64), 0, stream>>>(
        input, wih_hi, wih_lo, bias, whh_hi, hbuf, cws, flags, cur, nxt,
        (float*)d_out, k * TC, TC, (k == nch - 1) ? 1 : 0, (k < nch - 1) ? 1 : 0);
  }
}